// Round 19
// baseline (57.850 us; speedup 1.0000x reference)
//
#include <hip/hip_runtime.h>
#include <hip/hip_bf16.h>
#include <math.h>

typedef __attribute__((ext_vector_type(8))) short short8;
typedef __attribute__((ext_vector_type(4))) float f32x4;

#define MFMA(a, b, c) __builtin_amdgcn_mfma_f32_16x16x32_bf16(a, b, c, 0, 0, 0)

// ws layout (float offsets), ~5.2 MB
enum : int {
  WS_XB    = 0,        // [64][2048] bf16 (ushort view)       65536 floats
  WS_X2    = 65536,    // [64] f32 row sumsq of x                64
  WS_DMINP = 65600,    // [64][64] f32 per-block d2 col-minima 4096
  WS_SPART = 69696,    // [64][64] f32 row-sum partials of E   4096
  WS_PROB  = 73792,    // [64][1024] bf16 (E, unnormalized)   32768
  WS_SEL   = 106560,   // [64][2048] bf16                     65536
  WS_XNB   = 172096,   // [64][2048] bf16  (y = x + fast)     65536
  WS_XN2P  = 237632,   // [128][64] f32 partials ||y||^2       8192
  WS_CTB   = 245824,   // [2048][1024] bf16 centers^T       1048576 -> 1294400
};

__device__ inline short bfs(float f) {
  __hip_bfloat16 h = __float2bfloat16(f);
  return __builtin_bit_cast(short, h);
}
__device__ inline float bf2f(unsigned short u) {
  return __uint_as_float((unsigned)u << 16);
}

// async global->LDS, 16B per lane; LDS dest = wave-uniform base + lane*16
__device__ inline void gload16(const float* g, float* lds) {
  __builtin_amdgcn_global_load_lds(
      (const __attribute__((address_space(1))) unsigned int*)g,
      (__attribute__((address_space(3))) unsigned int*)lds, 16, 0, 0);
}

// ---- K1: blk<64: x -> bf16 XB, row sumsq, slow out.
//          blk>=64: centers -> CTB (bf16 transpose, zero-pad c>=1000) ----
__global__ __launch_bounds__(256) void k1(const float* __restrict__ x,
                                          const float* __restrict__ centers,
                                          float* __restrict__ out,
                                          float* __restrict__ ws) {
  __shared__ float A[64][65];
  int blk = blockIdx.x, t = threadIdx.x;
  int l = t & 63, w = t >> 6;
  if (blk < 64) {
    int b = blk;
    const float* xr = x + (size_t)b * 2048 + t * 8;
    float4 f0 = *(const float4*)(xr);
    float4 f1 = *(const float4*)(xr + 4);
    short8 h;
    h[0] = bfs(f0.x); h[1] = bfs(f0.y); h[2] = bfs(f0.z); h[3] = bfs(f0.w);
    h[4] = bfs(f1.x); h[5] = bfs(f1.y); h[6] = bfs(f1.z); h[7] = bfs(f1.w);
    *(short8*)((unsigned short*)(ws + WS_XB) + (size_t)b * 2048 + t * 8) = h;
    *(float4*)(out + 64000 + (size_t)b * 2048 + t * 8) = f0;
    *(float4*)(out + 64000 + (size_t)b * 2048 + t * 8 + 4) = f1;
    float s = f0.x*f0.x + f0.y*f0.y + f0.z*f0.z + f0.w*f0.w
            + f1.x*f1.x + f1.y*f1.y + f1.z*f1.z + f1.w*f1.w;
#pragma unroll
    for (int o = 32; o; o >>= 1) s += __shfl_xor(s, o);
    if (l == 0) A[0][w] = s;
    __syncthreads();
    if (t == 0) ws[WS_X2 + b] = A[0][0] + A[0][1] + A[0][2] + A[0][3];
  } else {
    int tid = blk - 64;                 // 0..511
    int tc = tid & 15, td = tid >> 4;   // c-tile 0..15, d-tile 0..31
    int c0 = tc * 64, d0 = td * 64;
    for (int r = 0; r < 16; ++r) {
      int cc = r * 4 + w;
      int c = c0 + cc;
      A[cc][l] = (c < 1000) ? centers[(size_t)c * 2048 + d0 + l] : 0.f;
    }
    __syncthreads();
    unsigned short* ctb = (unsigned short*)(ws + WS_CTB);
    for (int r = 0; r < 16; ++r) {
      int dd = r * 4 + w;
      ctb[(size_t)(d0 + dd) * 1024 + c0 + l] = (unsigned short)bfs(A[l][dd]);
    }
  }
}

// ---- K2: G123 full-K, 8 waves, 4-chunk (K=512) dbuf, 76 KB LDS -> 2 blk/CU
__global__ __launch_bounds__(512, 4) void k2(const float* __restrict__ centers,
                                             const float* __restrict__ fc1w,
                                             const float* __restrict__ fcw,
                                             const float* __restrict__ fc1b,
                                             const float* __restrict__ fcb,
                                             float* __restrict__ ws) {
  __shared__ float WT[2][16][516];   // 66 KB
  __shared__ f32x4 sacc[8][64];      // 8 KB
  __shared__ float ssq[8][64];       // 2 KB
  int blk = blockIdx.x, t = threadIdx.x;
  int w = t >> 6, l = t & 63;
  int ln = l & 15, lk = l >> 4;
  int n0 = blk * 16;
  bool cen = (n0 < 1024);

  auto stage = [&](int buf, int koff) {
    for (int r = 0; r < 2; ++r) {
      int row = w * 2 + r;
      int n = n0 + row;
      const float* brow;
      if (n < 1024)      brow = centers + (size_t)min(n, 999) * 2048;
      else if (n < 2048) brow = fc1w + (size_t)min(n - 1024, 999) * 2048;
      else               brow = fcw + (size_t)(n - 2048) * 2048;
#pragma unroll
      for (int j = 0; j < 2; ++j)
        gload16(brow + koff + j * 256 + l * 4, &WT[buf][row][j * 256]);
    }
  };

  int m0 = (w & 3) * 16;
  int kq = (w >> 2) * 256;           // K-half within each 512-chunk
  const unsigned short* aptr =
      (const unsigned short*)(ws + WS_XB) + (size_t)(m0 + ln) * 2048 + kq + lk * 8;

  stage(0, 0);
  __syncthreads();                   // chunk0 resident
  stage(1, 512);                     // in flight under chunk0 compute

  f32x4 acc = {0.f, 0.f, 0.f, 0.f};
  float sq = 0.f;

#pragma unroll
  for (int ch = 0; ch < 4; ++ch) {
    const float* wrow = &WT[ch & 1][ln][kq + lk * 8];
    const unsigned short* ap = aptr + ch * 512;
#pragma unroll
    for (int ks = 0; ks < 8; ++ks) {
      short8 a0 = *(const short8*)(ap + ks * 32);
      float4 f0 = *(const float4*)(wrow + ks * 32);
      float4 f1 = *(const float4*)(wrow + ks * 32 + 4);
      if (cen)
        sq += f0.x*f0.x + f0.y*f0.y + f0.z*f0.z + f0.w*f0.w
            + f1.x*f1.x + f1.y*f1.y + f1.z*f1.z + f1.w*f1.w;
      short8 bb;
      bb[0] = bfs(f0.x); bb[1] = bfs(f0.y); bb[2] = bfs(f0.z); bb[3] = bfs(f0.w);
      bb[4] = bfs(f1.x); bb[5] = bfs(f1.y); bb[6] = bfs(f1.z); bb[7] = bfs(f1.w);
      acc = MFMA(a0, bb, acc);
    }
    if (ch < 3) {
      __syncthreads();               // chunk ch+1 resident; WT[ch&1] free
      if (ch < 2) stage(ch & 1, (ch + 2) * 512);   // refill freed buffer
    }
  }

  sacc[w][l] = acc;
  ssq[w][l] = sq;
  __syncthreads();
  if (w < 4) {
    f32x4 a2 = sacc[w + 4][l];
    acc.x += a2.x; acc.y += a2.y; acc.z += a2.z; acc.w += a2.w;
    sq = ssq[w][l] + ssq[w + 4][l];

    if (cen) {
      sq += __shfl_xor(sq, 16);
      sq += __shfl_xor(sq, 32);          // c2 for col n0+ln
      int colv = n0 + ln;
#pragma unroll
      for (int j = 0; j < 4; ++j) {
        int m = m0 + lk * 4 + j;
        float d2 = (colv < 1000)
            ? fmaxf(ws[WS_X2 + m] - 2.f * acc[j] + sq, 0.f) : 3.0e38f;
        d2 = fminf(d2, __shfl_xor(d2, 1));
        d2 = fminf(d2, __shfl_xor(d2, 2));
        d2 = fminf(d2, __shfl_xor(d2, 4));
        d2 = fminf(d2, __shfl_xor(d2, 8));
        if (ln == 0) ws[WS_DMINP + blk * 64 + m] = d2;
      }
    } else if (n0 < 2048) {
      int c = n0 - 1024 + ln;
      unsigned short* pb = (unsigned short*)(ws + WS_PROB);
#pragma unroll
      for (int j = 0; j < 4; ++j) {
        int m = m0 + lk * 4 + j;
        float e = (c < 1000) ? __expf(acc[j] + fc1b[c]) : 0.f;
        pb[(size_t)m * 1024 + c] = (unsigned short)bfs(e);
        float s = e;
        s += __shfl_xor(s, 1);
        s += __shfl_xor(s, 2);
        s += __shfl_xor(s, 4);
        s += __shfl_xor(s, 8);
        if (ln == 0) ws[WS_SPART + (blk - 64) * 64 + m] = s;
      }
    } else {
      int d = n0 - 2048 + ln;
      unsigned short* sel = (unsigned short*)(ws + WS_SEL);
#pragma unroll
      for (int j = 0; j < 4; ++j) {
        int m = m0 + lk * 4 + j;
        float sv = tanhf(acc[j] + fcb[d]);
        sel[(size_t)m * 2048 + d] = (unsigned short)bfs(sv);
      }
    }
  }
}

// ---- KDE: G4 = E @ centers via CTB (short8 B loads) + fused y epilogue ----
__global__ __launch_bounds__(256) void kde(const float* __restrict__ x,
                                           float* __restrict__ out,
                                           float* __restrict__ ws) {
  __shared__ f32x4 sacc[4][2][64];
  __shared__ float sinv[64];
  int blk = blockIdx.x, t = threadIdx.x;
  int w = t >> 6, l = t & 63;
  int cs = blk >> 1, mh = blk & 1;
  int d0 = cs * 16, m0 = mh * 32;
  int ln = l & 15, lk = l >> 4;
  int k0 = w * 256;
  if (t < 64) {
    float s = 0.f;
#pragma unroll
    for (int i = 0; i < 64; ++i) s += ws[WS_SPART + i * 64 + t];
    sinv[t] = 1.0f / s;
  }
  const unsigned short* aptr =
      (const unsigned short*)(ws + WS_PROB) + (size_t)(m0 + ln) * 1024 + k0 + lk * 8;
  const unsigned short* brow =
      (const unsigned short*)(ws + WS_CTB) + (size_t)(d0 + ln) * 1024 + k0 + lk * 8;
  f32x4 acc0 = {0.f, 0.f, 0.f, 0.f}, acc1 = {0.f, 0.f, 0.f, 0.f};
#pragma unroll
  for (int ks = 0; ks < 8; ++ks) {
    short8 a0 = *(const short8*)(aptr + ks * 32);
    short8 a1 = *(const short8*)(aptr + 16 * 1024 + ks * 32);
    short8 bb = *(const short8*)(brow + ks * 32);
    acc0 = MFMA(a0, bb, acc0);
    acc1 = MFMA(a1, bb, acc1);
  }
  sacc[w][0][l] = acc0;
  sacc[w][1][l] = acc1;
  __syncthreads();
  if (w == 0) {
    f32x4 r0 = sacc[0][0][l], r1 = sacc[0][1][l];
#pragma unroll
    for (int i = 1; i < 4; ++i) {
      f32x4 u0 = sacc[i][0][l], u1 = sacc[i][1][l];
      r0.x += u0.x; r0.y += u0.y; r0.z += u0.z; r0.w += u0.w;
      r1.x += u1.x; r1.y += u1.y; r1.z += u1.z; r1.w += u1.w;
    }
    const unsigned short* sel = (const unsigned short*)(ws + WS_SEL);
    unsigned short* xnb = (unsigned short*)(ws + WS_XNB);
    float rr[8] = {r0.x, r0.y, r0.z, r0.w, r1.x, r1.y, r1.z, r1.w};
#pragma unroll
    for (int q = 0; q < 8; ++q) {
      int b = m0 + (q >> 2) * 16 + lk * 4 + (q & 3);
      int d = d0 + ln;
      float cc = rr[q] * sinv[b];
      float sv = bf2f(sel[(size_t)b * 2048 + d]);
      float xv = x[(size_t)b * 2048 + d];
      float fast = sv * cc;
      out[195072 + (size_t)b * 2048 + d] = fast;
      float yv = xv + fast;
      xnb[(size_t)b * 2048 + d] = (unsigned short)bfs(yv);
      float sq = yv * yv;
      sq += __shfl_xor(sq, 1);
      sq += __shfl_xor(sq, 2);
      sq += __shfl_xor(sq, 4);
      sq += __shfl_xor(sq, 8);
      if (ln == 0) ws[WS_XN2P + cs * 64 + b] = sq;
    }
  }
}

// ---- K7: G5 full-K, 128 blocks x 8 cols (2x CU coverage), dbuf staging,
// fused cosnorm epilogue. Cols duplicated across ln/ln+8 (write-guarded).
__global__ __launch_bounds__(512) void k7(const float* __restrict__ cosw,
                                          float* __restrict__ out,
                                          float* __restrict__ ws) {
  __shared__ float WT[2][8][1028];   // 65.8 KB
  __shared__ f32x4 sacc[8][64];
  __shared__ float ssq[8][64];
  __shared__ float scale_s[64];
  int blk = blockIdx.x, t = threadIdx.x;
  int w = t >> 6, l = t & 63;
  int ln = l & 15, lk = l >> 4;
  int n0 = blk * 8;                  // 128 blocks x 8 cols = 1024 >= 1000

  if (t < 64) {   // scale[m] = 16*conf/(1+conf*||y||)
    float s = 0.f;
    for (int i = 0; i < 128; ++i) s += ws[WS_XN2P + i * 64 + t];
    float ny = sqrtf(fmaxf(s, 0.f));
    float d2 = 3.0e38f;
    for (int i = 0; i < 64; ++i) d2 = fminf(d2, ws[WS_DMINP + i * 64 + t]);
    float cf = 10.0f * rsqrtf(fmaxf(d2, 1e-20f));
    scale_s[t] = 16.0f * cf / (1.0f + cf * ny);
  }

  auto stage = [&](int buf, int koff) {
    int row = w;                     // 8 waves, 1 row each
    const float* brow = cosw + (size_t)min(n0 + row, 999) * 2048;
#pragma unroll
    for (int j = 0; j < 4; ++j)
      gload16(brow + koff + j * 256 + l * 4, &WT[buf][row][j * 256]);
  };

  stage(0, 0);
  __syncthreads();
  stage(1, 1024);

  int m0 = (w & 3) * 16;
  int kq = (w >> 2) * 512;
  const unsigned short* aptr =
      (const unsigned short*)(ws + WS_XNB) + (size_t)(m0 + ln) * 2048 + kq + lk * 8;
  f32x4 acc = {0.f, 0.f, 0.f, 0.f};
  float sq = 0.f;

#pragma unroll 2
  for (int ch = 0; ch < 2; ++ch) {
    if (ch == 1) __syncthreads();
    const float* wrow = &WT[ch][ln & 7][kq + lk * 8];
    const unsigned short* ap = aptr + ch * 1024;
#pragma unroll 4
    for (int ks = 0; ks < 16; ++ks) {
      short8 a0 = *(const short8*)(ap + ks * 32);
      float4 f0 = *(const float4*)(wrow + ks * 32);
      float4 f1 = *(const float4*)(wrow + ks * 32 + 4);
      sq += f0.x*f0.x + f0.y*f0.y + f0.z*f0.z + f0.w*f0.w
          + f1.x*f1.x + f1.y*f1.y + f1.z*f1.z + f1.w*f1.w;
      short8 bb;
      bb[0] = bfs(f0.x); bb[1] = bfs(f0.y); bb[2] = bfs(f0.z); bb[3] = bfs(f0.w);
      bb[4] = bfs(f1.x); bb[5] = bfs(f1.y); bb[6] = bfs(f1.z); bb[7] = bfs(f1.w);
      acc = MFMA(a0, bb, acc);
    }
  }

  sacc[w][l] = acc;
  ssq[w][l] = sq;
  __syncthreads();
  if (w < 4) {
    f32x4 a2 = sacc[w + 4][l];
    acc.x += a2.x; acc.y += a2.y; acc.z += a2.z; acc.w += a2.w;
    sq = ssq[w][l] + ssq[w + 4][l];
    sq += __shfl_xor(sq, 16);
    sq += __shfl_xor(sq, 32);           // ||w_c||^2 for col n0+(ln&7)
    float invw = rsqrtf(fmaxf(sq, 1e-30f));
    int c = n0 + (ln & 7);
    if (ln < 8 && c < 1000) {           // ln>=8 duplicates ln-8: skip
#pragma unroll
      for (int j = 0; j < 4; ++j) {
        int m = m0 + lk * 4 + j;
        out[(size_t)m * 1000 + c] = acc[j] * invw * scale_s[m];
      }
    }
  }
}

extern "C" void kernel_launch(void* const* d_in, const int* in_sizes, int n_in,
                              void* d_out, int out_size, void* d_ws, size_t ws_size,
                              hipStream_t stream) {
  const float* x       = (const float*)d_in[0];
  const float* centers = (const float*)d_in[2];
  const float* fcw     = (const float*)d_in[4];
  const float* fcb     = (const float*)d_in[5];
  const float* fc1w    = (const float*)d_in[6];
  const float* fc1b    = (const float*)d_in[7];
  const float* cosw    = (const float*)d_in[8];
  float* out = (float*)d_out;
  float* ws  = (float*)d_ws;

  hipLaunchKernelGGL(k1,  dim3(576), dim3(256), 0, stream, x, centers, out, ws);
  hipLaunchKernelGGL(k2,  dim3(256), dim3(512), 0, stream, centers, fc1w, fcw, fc1b, fcb, ws);
  hipLaunchKernelGGL(kde, dim3(256), dim3(256), 0, stream, x, out, ws);
  hipLaunchKernelGGL(k7,  dim3(128), dim3(512), 0, stream, cosw, out, ws);
}

// Round 20
// 57.382 us; speedup vs baseline: 1.0082x; 1.0082x over previous
//
#include <hip/hip_runtime.h>
#include <hip/hip_bf16.h>
#include <math.h>

typedef __attribute__((ext_vector_type(8))) short short8;
typedef __attribute__((ext_vector_type(4))) float f32x4;

#define MFMA(a, b, c) __builtin_amdgcn_mfma_f32_16x16x32_bf16(a, b, c, 0, 0, 0)

// ws layout (float offsets), ~5.2 MB
enum : int {
  WS_XB    = 0,        // [64][2048] bf16 (ushort view)       65536 floats
  WS_X2    = 65536,    // [64] f32 row sumsq of x                64
  WS_DMINP = 65600,    // [64][64] f32 per-block d2 col-minima 4096
  WS_SPART = 69696,    // [64][64] f32 row-sum partials of E   4096
  WS_PROB  = 73792,    // [64][1024] bf16 (E, unnormalized)   32768
  WS_SEL   = 106560,   // [64][2048] bf16                     65536
  WS_XNB   = 172096,   // [64][2048] bf16  (y = x + fast)     65536
  WS_XN2P  = 237632,   // [128][64] f32 partials ||y||^2       8192
  WS_CTB   = 245824,   // [2048][1024] bf16 centers^T       1048576 -> 1294400
};

__device__ inline short bfs(float f) {
  __hip_bfloat16 h = __float2bfloat16(f);
  return __builtin_bit_cast(short, h);
}
__device__ inline float bf2f(unsigned short u) {
  return __uint_as_float((unsigned)u << 16);
}

// async global->LDS, 16B per lane; LDS dest = wave-uniform base + lane*16
__device__ inline void gload16(const float* g, float* lds) {
  __builtin_amdgcn_global_load_lds(
      (const __attribute__((address_space(1))) unsigned int*)g,
      (__attribute__((address_space(3))) unsigned int*)lds, 16, 0, 0);
}

// ---- K1: blk<64: x -> bf16 XB, row sumsq, slow out.
//          blk>=64: centers -> CTB (bf16 transpose, zero-pad c>=1000) ----
__global__ __launch_bounds__(256) void k1(const float* __restrict__ x,
                                          const float* __restrict__ centers,
                                          float* __restrict__ out,
                                          float* __restrict__ ws) {
  __shared__ float A[64][65];
  int blk = blockIdx.x, t = threadIdx.x;
  int l = t & 63, w = t >> 6;
  if (blk < 64) {
    int b = blk;
    const float* xr = x + (size_t)b * 2048 + t * 8;
    float4 f0 = *(const float4*)(xr);
    float4 f1 = *(const float4*)(xr + 4);
    short8 h;
    h[0] = bfs(f0.x); h[1] = bfs(f0.y); h[2] = bfs(f0.z); h[3] = bfs(f0.w);
    h[4] = bfs(f1.x); h[5] = bfs(f1.y); h[6] = bfs(f1.z); h[7] = bfs(f1.w);
    *(short8*)((unsigned short*)(ws + WS_XB) + (size_t)b * 2048 + t * 8) = h;
    *(float4*)(out + 64000 + (size_t)b * 2048 + t * 8) = f0;
    *(float4*)(out + 64000 + (size_t)b * 2048 + t * 8 + 4) = f1;
    float s = f0.x*f0.x + f0.y*f0.y + f0.z*f0.z + f0.w*f0.w
            + f1.x*f1.x + f1.y*f1.y + f1.z*f1.z + f1.w*f1.w;
#pragma unroll
    for (int o = 32; o; o >>= 1) s += __shfl_xor(s, o);
    if (l == 0) A[0][w] = s;
    __syncthreads();
    if (t == 0) ws[WS_X2 + b] = A[0][0] + A[0][1] + A[0][2] + A[0][3];
  } else {
    int tid = blk - 64;                 // 0..511
    int tc = tid & 15, td = tid >> 4;   // c-tile 0..15, d-tile 0..31
    int c0 = tc * 64, d0 = td * 64;
    for (int r = 0; r < 16; ++r) {
      int cc = r * 4 + w;
      int c = c0 + cc;
      A[cc][l] = (c < 1000) ? centers[(size_t)c * 2048 + d0 + l] : 0.f;
    }
    __syncthreads();
    unsigned short* ctb = (unsigned short*)(ws + WS_CTB);
    for (int r = 0; r < 16; ++r) {
      int dd = r * 4 + w;
      ctb[(size_t)(d0 + dd) * 1024 + c0 + l] = (unsigned short)bfs(A[l][dd]);
    }
  }
}

// ---- K2: G123 full-K, 8 waves, 4-chunk (K=512) dbuf, 76 KB LDS -> 2 blk/CU
__global__ __launch_bounds__(512, 4) void k2(const float* __restrict__ centers,
                                             const float* __restrict__ fc1w,
                                             const float* __restrict__ fcw,
                                             const float* __restrict__ fc1b,
                                             const float* __restrict__ fcb,
                                             float* __restrict__ ws) {
  __shared__ float WT[2][16][516];   // 66 KB
  __shared__ f32x4 sacc[8][64];      // 8 KB
  __shared__ float ssq[8][64];       // 2 KB
  int blk = blockIdx.x, t = threadIdx.x;
  int w = t >> 6, l = t & 63;
  int ln = l & 15, lk = l >> 4;
  int n0 = blk * 16;
  bool cen = (n0 < 1024);

  auto stage = [&](int buf, int koff) {
    for (int r = 0; r < 2; ++r) {
      int row = w * 2 + r;
      int n = n0 + row;
      const float* brow;
      if (n < 1024)      brow = centers + (size_t)min(n, 999) * 2048;
      else if (n < 2048) brow = fc1w + (size_t)min(n - 1024, 999) * 2048;
      else               brow = fcw + (size_t)(n - 2048) * 2048;
#pragma unroll
      for (int j = 0; j < 2; ++j)
        gload16(brow + koff + j * 256 + l * 4, &WT[buf][row][j * 256]);
    }
  };

  int m0 = (w & 3) * 16;
  int kq = (w >> 2) * 256;           // K-half within each 512-chunk
  const unsigned short* aptr =
      (const unsigned short*)(ws + WS_XB) + (size_t)(m0 + ln) * 2048 + kq + lk * 8;

  stage(0, 0);
  __syncthreads();                   // chunk0 resident
  stage(1, 512);                     // in flight under chunk0 compute

  f32x4 acc = {0.f, 0.f, 0.f, 0.f};
  float sq = 0.f;

#pragma unroll
  for (int ch = 0; ch < 4; ++ch) {
    const float* wrow = &WT[ch & 1][ln][kq + lk * 8];
    const unsigned short* ap = aptr + ch * 512;
#pragma unroll
    for (int ks = 0; ks < 8; ++ks) {
      short8 a0 = *(const short8*)(ap + ks * 32);
      float4 f0 = *(const float4*)(wrow + ks * 32);
      float4 f1 = *(const float4*)(wrow + ks * 32 + 4);
      if (cen)
        sq += f0.x*f0.x + f0.y*f0.y + f0.z*f0.z + f0.w*f0.w
            + f1.x*f1.x + f1.y*f1.y + f1.z*f1.z + f1.w*f1.w;
      short8 bb;
      bb[0] = bfs(f0.x); bb[1] = bfs(f0.y); bb[2] = bfs(f0.z); bb[3] = bfs(f0.w);
      bb[4] = bfs(f1.x); bb[5] = bfs(f1.y); bb[6] = bfs(f1.z); bb[7] = bfs(f1.w);
      acc = MFMA(a0, bb, acc);
    }
    if (ch < 3) {
      __syncthreads();               // chunk ch+1 resident; WT[ch&1] free
      if (ch < 2) stage(ch & 1, (ch + 2) * 512);   // refill freed buffer
    }
  }

  sacc[w][l] = acc;
  ssq[w][l] = sq;
  __syncthreads();
  if (w < 4) {
    f32x4 a2 = sacc[w + 4][l];
    acc.x += a2.x; acc.y += a2.y; acc.z += a2.z; acc.w += a2.w;
    sq = ssq[w][l] + ssq[w + 4][l];

    if (cen) {
      sq += __shfl_xor(sq, 16);
      sq += __shfl_xor(sq, 32);          // c2 for col n0+ln
      int colv = n0 + ln;
#pragma unroll
      for (int j = 0; j < 4; ++j) {
        int m = m0 + lk * 4 + j;
        float d2 = (colv < 1000)
            ? fmaxf(ws[WS_X2 + m] - 2.f * acc[j] + sq, 0.f) : 3.0e38f;
        d2 = fminf(d2, __shfl_xor(d2, 1));
        d2 = fminf(d2, __shfl_xor(d2, 2));
        d2 = fminf(d2, __shfl_xor(d2, 4));
        d2 = fminf(d2, __shfl_xor(d2, 8));
        if (ln == 0) ws[WS_DMINP + blk * 64 + m] = d2;
      }
    } else if (n0 < 2048) {
      int c = n0 - 1024 + ln;
      unsigned short* pb = (unsigned short*)(ws + WS_PROB);
#pragma unroll
      for (int j = 0; j < 4; ++j) {
        int m = m0 + lk * 4 + j;
        float e = (c < 1000) ? __expf(acc[j] + fc1b[c]) : 0.f;
        pb[(size_t)m * 1024 + c] = (unsigned short)bfs(e);
        float s = e;
        s += __shfl_xor(s, 1);
        s += __shfl_xor(s, 2);
        s += __shfl_xor(s, 4);
        s += __shfl_xor(s, 8);
        if (ln == 0) ws[WS_SPART + (blk - 64) * 64 + m] = s;
      }
    } else {
      int d = n0 - 2048 + ln;
      unsigned short* sel = (unsigned short*)(ws + WS_SEL);
#pragma unroll
      for (int j = 0; j < 4; ++j) {
        int m = m0 + lk * 4 + j;
        float sv = tanhf(acc[j] + fcb[d]);
        sel[(size_t)m * 2048 + d] = (unsigned short)bfs(sv);
      }
    }
  }
}

// ---- KDE: G4 = E @ centers via CTB (short8 B loads) + fused y epilogue ----
__global__ __launch_bounds__(256) void kde(const float* __restrict__ x,
                                           float* __restrict__ out,
                                           float* __restrict__ ws) {
  __shared__ f32x4 sacc[4][2][64];
  __shared__ float sinv[64];
  int blk = blockIdx.x, t = threadIdx.x;
  int w = t >> 6, l = t & 63;
  int cs = blk >> 1, mh = blk & 1;
  int d0 = cs * 16, m0 = mh * 32;
  int ln = l & 15, lk = l >> 4;
  int k0 = w * 256;
  if (t < 64) {
    float s = 0.f;
#pragma unroll
    for (int i = 0; i < 64; ++i) s += ws[WS_SPART + i * 64 + t];
    sinv[t] = 1.0f / s;
  }
  const unsigned short* aptr =
      (const unsigned short*)(ws + WS_PROB) + (size_t)(m0 + ln) * 1024 + k0 + lk * 8;
  const unsigned short* brow =
      (const unsigned short*)(ws + WS_CTB) + (size_t)(d0 + ln) * 1024 + k0 + lk * 8;
  f32x4 acc0 = {0.f, 0.f, 0.f, 0.f}, acc1 = {0.f, 0.f, 0.f, 0.f};
#pragma unroll
  for (int ks = 0; ks < 8; ++ks) {
    short8 a0 = *(const short8*)(aptr + ks * 32);
    short8 a1 = *(const short8*)(aptr + 16 * 1024 + ks * 32);
    short8 bb = *(const short8*)(brow + ks * 32);
    acc0 = MFMA(a0, bb, acc0);
    acc1 = MFMA(a1, bb, acc1);
  }
  sacc[w][0][l] = acc0;
  sacc[w][1][l] = acc1;
  __syncthreads();
  if (w == 0) {
    f32x4 r0 = sacc[0][0][l], r1 = sacc[0][1][l];
#pragma unroll
    for (int i = 1; i < 4; ++i) {
      f32x4 u0 = sacc[i][0][l], u1 = sacc[i][1][l];
      r0.x += u0.x; r0.y += u0.y; r0.z += u0.z; r0.w += u0.w;
      r1.x += u1.x; r1.y += u1.y; r1.z += u1.z; r1.w += u1.w;
    }
    const unsigned short* sel = (const unsigned short*)(ws + WS_SEL);
    unsigned short* xnb = (unsigned short*)(ws + WS_XNB);
    float rr[8] = {r0.x, r0.y, r0.z, r0.w, r1.x, r1.y, r1.z, r1.w};
#pragma unroll
    for (int q = 0; q < 8; ++q) {
      int b = m0 + (q >> 2) * 16 + lk * 4 + (q & 3);
      int d = d0 + ln;
      float cc = rr[q] * sinv[b];
      float sv = bf2f(sel[(size_t)b * 2048 + d]);
      float xv = x[(size_t)b * 2048 + d];
      float fast = sv * cc;
      out[195072 + (size_t)b * 2048 + d] = fast;
      float yv = xv + fast;
      xnb[(size_t)b * 2048 + d] = (unsigned short)bfs(yv);
      float sq = yv * yv;
      sq += __shfl_xor(sq, 1);
      sq += __shfl_xor(sq, 2);
      sq += __shfl_xor(sq, 4);
      sq += __shfl_xor(sq, 8);
      if (ln == 0) ws[WS_XN2P + cs * 64 + b] = sq;
    }
  }
}

// ---- K7: G5 full-K (dbuf staging) + fused cosnorm epilogue -> logits ----
__global__ __launch_bounds__(512) void k7(const float* __restrict__ cosw,
                                          float* __restrict__ out,
                                          float* __restrict__ ws) {
  __shared__ float WT[2][16][1028];
  __shared__ f32x4 sacc[8][64];
  __shared__ float ssq[8][64];
  __shared__ float scale_s[64];
  int blk = blockIdx.x, t = threadIdx.x;
  int w = t >> 6, l = t & 63;
  int ln = l & 15, lk = l >> 4;
  int n0 = blk * 16;

  if (t < 64) {   // scale[m] = 16*conf/(1+conf*||y||)
    float s = 0.f;
    for (int i = 0; i < 128; ++i) s += ws[WS_XN2P + i * 64 + t];
    float ny = sqrtf(fmaxf(s, 0.f));
    float d2 = 3.0e38f;
    for (int i = 0; i < 64; ++i) d2 = fminf(d2, ws[WS_DMINP + i * 64 + t]);
    float cf = 10.0f * rsqrtf(fmaxf(d2, 1e-20f));
    scale_s[t] = 16.0f * cf / (1.0f + cf * ny);
  }

  auto stage = [&](int buf, int koff) {
    for (int r = 0; r < 2; ++r) {
      int row = w * 2 + r;
      const float* brow = cosw + (size_t)min(n0 + row, 999) * 2048;
#pragma unroll
      for (int j = 0; j < 4; ++j)
        gload16(brow + koff + j * 256 + l * 4, &WT[buf][row][j * 256]);
    }
  };

  stage(0, 0);
  __syncthreads();
  stage(1, 1024);

  int m0 = (w & 3) * 16;
  int kq = (w >> 2) * 512;
  const unsigned short* aptr =
      (const unsigned short*)(ws + WS_XNB) + (size_t)(m0 + ln) * 2048 + kq + lk * 8;
  f32x4 acc = {0.f, 0.f, 0.f, 0.f};
  float sq = 0.f;

#pragma unroll 2
  for (int ch = 0; ch < 2; ++ch) {
    if (ch == 1) __syncthreads();
    const float* wrow = &WT[ch][ln][kq + lk * 8];
    const unsigned short* ap = aptr + ch * 1024;
#pragma unroll 4
    for (int ks = 0; ks < 16; ++ks) {
      short8 a0 = *(const short8*)(ap + ks * 32);
      float4 f0 = *(const float4*)(wrow + ks * 32);
      float4 f1 = *(const float4*)(wrow + ks * 32 + 4);
      sq += f0.x*f0.x + f0.y*f0.y + f0.z*f0.z + f0.w*f0.w
          + f1.x*f1.x + f1.y*f1.y + f1.z*f1.z + f1.w*f1.w;
      short8 bb;
      bb[0] = bfs(f0.x); bb[1] = bfs(f0.y); bb[2] = bfs(f0.z); bb[3] = bfs(f0.w);
      bb[4] = bfs(f1.x); bb[5] = bfs(f1.y); bb[6] = bfs(f1.z); bb[7] = bfs(f1.w);
      acc = MFMA(a0, bb, acc);
    }
  }

  sacc[w][l] = acc;
  ssq[w][l] = sq;
  __syncthreads();
  if (w < 4) {
    f32x4 a2 = sacc[w + 4][l];
    acc.x += a2.x; acc.y += a2.y; acc.z += a2.z; acc.w += a2.w;
    sq = ssq[w][l] + ssq[w + 4][l];
    sq += __shfl_xor(sq, 16);
    sq += __shfl_xor(sq, 32);           // ||w_c||^2 for col n0+ln
    float invw = rsqrtf(fmaxf(sq, 1e-30f));
    int c = n0 + ln;
    if (c < 1000) {
#pragma unroll
      for (int j = 0; j < 4; ++j) {
        int m = m0 + lk * 4 + j;
        out[(size_t)m * 1000 + c] = acc[j] * invw * scale_s[m];
      }
    }
  }
}

extern "C" void kernel_launch(void* const* d_in, const int* in_sizes, int n_in,
                              void* d_out, int out_size, void* d_ws, size_t ws_size,
                              hipStream_t stream) {
  const float* x       = (const float*)d_in[0];
  const float* centers = (const float*)d_in[2];
  const float* fcw     = (const float*)d_in[4];
  const float* fcb     = (const float*)d_in[5];
  const float* fc1w    = (const float*)d_in[6];
  const float* fc1b    = (const float*)d_in[7];
  const float* cosw    = (const float*)d_in[8];
  float* out = (float*)d_out;
  float* ws  = (float*)d_ws;

  hipLaunchKernelGGL(k1,  dim3(576), dim3(256), 0, stream, x, centers, out, ws);
  hipLaunchKernelGGL(k2,  dim3(256), dim3(512), 0, stream, centers, fc1w, fcw, fc1b, fcb, ws);
  hipLaunchKernelGGL(kde, dim3(256), dim3(256), 0, stream, x, out, ws);
  hipLaunchKernelGGL(k7,  dim3(128), dim3(512), 0, stream, cosw, out, ws);
}